// Round 13
// baseline (231.537 us; speedup 1.0000x reference)
//
#include <hip/hip_runtime.h>
#include <hip/hip_bf16.h>

#define N_Q   16384
#define MCTX  4096
#define DSIN  256
#define YDIM  7
#define PDIM  256   // SPROJ
#define BK    32

typedef __attribute__((ext_vector_type(8))) short s16x8;   // 8 bf16 (4 VGPRs)
typedef __attribute__((ext_vector_type(4))) float f32x4;   // MFMA C/D frag
typedef unsigned short u16;

static __device__ __forceinline__ u16 f2bf(float f) {
    union { float f; unsigned u; } v; v.f = f;
    unsigned r = v.u + 0x7fffu + ((v.u >> 16) & 1u);  // RNE
    return (u16)(r >> 16);
}
static __device__ __forceinline__ float bf2f(u16 h) {
    union { unsigned u; float f; } v; v.u = ((unsigned)h) << 16;
    return v.f;
}
static __device__ __forceinline__ f32x4 mfma16(s16x8 a, s16x8 b, f32x4 c) {
    return __builtin_amdgcn_mfma_f32_16x16x32_bf16(a, b, c, 0, 0, 0);
}
// async 16B global->LDS DMA (dst = wave-uniform base + lane*16)
static __device__ __forceinline__ void gload_lds16(const u16* g, u16* l) {
    __builtin_amdgcn_global_load_lds(
        (const __attribute__((address_space(1))) unsigned int*)(g),
        (__attribute__((address_space(3))) unsigned int*)(l), 16, 0, 0);
}

// ---------------- K_prep: (a) Wq transpose + hi/lo split, (b) YK + YVb ----------------
__global__ void k_prep(const float* __restrict__ Wq, u16* __restrict__ WtH,
                       u16* __restrict__ WtL, const float* __restrict__ y,
                       const float* __restrict__ Wk, const float* __restrict__ Wv,
                       u16* __restrict__ YK, u16* __restrict__ YVb) {
    if (blockIdx.x < PDIM) {
        int n = blockIdx.x;   // 0..PDIM-1
        int k = threadIdx.x;  // 0..DSIN-1
        float w = Wq[(size_t)k * PDIM + n];
        u16 h = f2bf(w);
        WtH[(size_t)n * DSIN + k] = h;
        WtL[(size_t)n * DSIN + k] = f2bf(w - bf2f(h));
    } else {
        // YK scaled 1/16 row-major [key][p]; YVb coalesced PV-frag layout [kb][p][32]
        int kb = blockIdx.x - PDIM;  // key block (32 keys)
        int p  = threadIdx.x;        // proj
        float wk[YDIM], wv[YDIM];
#pragma unroll
        for (int j = 0; j < YDIM; ++j) {
            wk[j] = Wk[(size_t)j * PDIM + p];
            wv[j] = Wv[(size_t)j * PDIM + p];
        }
        u16 vbuf[32];
#pragma unroll
        for (int m = 0; m < 32; ++m) {
            int key = kb * 32 + m;
            float ak = 0.f, av = 0.f;
#pragma unroll
            for (int j = 0; j < YDIM; ++j) {
                float yy = y[(size_t)key * YDIM + j];
                ak += yy * wk[j];
                av += yy * wv[j];
            }
            YK[(size_t)key * PDIM + p] = f2bf(ak * 0.0625f);  // fold 1/sqrt(256)
            vbuf[m] = f2bf(av);
        }
        s16x8* dst = (s16x8*)(YVb + ((size_t)kb * PDIM + p) * 32);
#pragma unroll
        for (int c = 0; c < 4; ++c) dst[c] = ((s16x8*)vbuf)[c];
    }
}

// ---------------- K1: XQ = x @ Wq, hi/lo split; 32-row tiles, 2 blocks/CU ----------------
__global__ __launch_bounds__(256, 2) void k_xq(const float* __restrict__ x,
                                               const u16* __restrict__ WtH,
                                               const u16* __restrict__ WtL,
                                               u16* __restrict__ XQ) {
    __shared__ u16 xH[32 * 256];  // XOR-swizzled 16B chunks: phys c = c ^ (row&7)
    __shared__ u16 xL[32 * 256];
    const int tid = threadIdx.x;
    const int rowg0 = blockIdx.x * 32;
#pragma unroll
    for (int i = 0; i < 4; ++i) {
        int row = (tid >> 5) + i * 8;
        int c32 = tid & 31;
        const float* px = x + (size_t)(rowg0 + row) * DSIN + c32 * 8;
        float4 a = *(const float4*)px;
        float4 b = *(const float4*)(px + 4);
        float vals[8] = {a.x, a.y, a.z, a.w, b.x, b.y, b.z, b.w};
        s16x8 h, l;
#pragma unroll
        for (int j = 0; j < 8; ++j) {
            u16 hh = f2bf(vals[j]);
            h[j] = (short)hh;
            l[j] = (short)f2bf(vals[j] - bf2f(hh));
        }
        int pc = c32 ^ (row & 7);
        *(s16x8*)(xH + row * 256 + pc * 8) = h;
        *(s16x8*)(xL + row * 256 + pc * 8) = l;
    }
    __syncthreads();

    const int wave = tid >> 6, lane = tid & 63;
    const int quad = lane >> 4, m16 = lane & 15;
    const int rh = wave & 1, ph = wave >> 1;
    const int rowl = rh * 16 + m16;
    const int swz = rowl & 7;
    s16x8 ah[8], al[8];
#pragma unroll
    for (int kf = 0; kf < 8; ++kf) {
        int pc = (kf * 4 + quad) ^ swz;
        ah[kf] = *(const s16x8*)(xH + rowl * 256 + pc * 8);
        al[kf] = *(const s16x8*)(xL + rowl * 256 + pc * 8);
    }
#pragma unroll
    for (int ptl = 0; ptl < 8; ++ptl) {
        int pt = ph * 8 + ptl;
        f32x4 acc = (f32x4){0.f, 0.f, 0.f, 0.f};
#pragma unroll
        for (int kf = 0; kf < 8; ++kf) {
            size_t idx = (size_t)(pt * 16 + m16) * DSIN + kf * 32 + quad * 8;
            s16x8 bh = *(const s16x8*)(WtH + idx);
            s16x8 bl = *(const s16x8*)(WtL + idx);
            acc = mfma16(ah[kf], bh, acc);
            acc = mfma16(al[kf], bh, acc);
            acc = mfma16(ah[kf], bl, acc);
        }
#pragma unroll
        for (int r = 0; r < 4; ++r)
            XQ[(size_t)(rowg0 + rh * 16 + quad * 4 + r) * PDIM + pt * 16 + m16] =
                f2bf(acc[r]);
    }
}

// ---------------- K3: fused attention — sigma-swapped QK, P in registers, K+V DMA'd ----
// Wave w owns q-rows [w*16,w*16+16) end-to-end: swapped QK (A=Kt sigma-permuted rows,
// B=qf) puts lane (quad,m16)'s S values at keys quad*8+{0..7} for q=m16 — exactly the
// PV A-frag (R10's verified mapping). P: MFMA -> exp/relu -> pack -> MFMA, in-register.
// No cross-wave dependency -> ONE barrier/iter; Kt AND Vt double-buffered, DMA-prefetched
// with a FULL-iteration window. Vt chunks frag-ordered: chunk pt*64+lane holds
// V[keys (lane>>4)*8..+8)][p=pt*16+(lane&15)] -> PV reads are linear, conflict-free.
__global__ __launch_bounds__(256, 2) void k_attn(const u16* __restrict__ XQ,
                                                 const u16* __restrict__ YK,
                                                 const u16* __restrict__ YVb,
                                                 u16* __restrict__ accE,
                                                 u16* __restrict__ accR,
                                                 float* __restrict__ lsum,
                                                 float* __restrict__ rsum,
                                                 int msPerSplit) {
    __shared__ u16 Kt[2][32 * 256];  // 16KB x2, XOR-swizzled chunks, sigma rows
    __shared__ u16 Vt[2][32 * 256];  // 16KB x2, frag-ordered chunks

    const int tid = threadIdx.x;
    const int wave = tid >> 6, lane = tid & 63;
    const int quad = lane >> 4, m16 = lane & 15;
    const int split = blockIdx.y;
    const int qbase = blockIdx.x * 64;
    const int key_begin = split * msPerSplit;
    const int iters = msPerSplit / BK;
    const int swz = m16 & 7;

    // Q frags for this wave's 16 q-rows (MFMA B operand; same per-lane content)
    s16x8 qf[8];
    const u16* qp = XQ + (size_t)(qbase + wave * 16 + m16) * DSIN;
#pragma unroll
    for (int kf = 0; kf < 8; ++kf)
        qf[kf] = *(const s16x8*)(qp + kf * 32 + quad * 8);

    f32x4 aE[16], aR[16];
#pragma unroll
    for (int t = 0; t < 16; ++t) {
        aE[t] = (f32x4){0.f, 0.f, 0.f, 0.f};
        aR[t] = (f32x4){0.f, 0.f, 0.f, 0.f};
    }
    float lacc = 0.f, racc = 0.f;

    // K: Kt row r <- key key0 + sigma(r), sigma = (r>>2)&3)*8 + (r&3) + 4*(r>>4)
    auto stageK = [&](int key0, int b) {
#pragma unroll
        for (int c = 0; c < 4; ++c) {
            int L = (wave * 4 + c) * 64 + lane;   // phys chunk 0..1023
            int r = L >> 5;                        // Kt row 0..31
            int sg = ((r >> 2) & 3) * 8 + (r & 3) + ((r >> 4) << 2);
            int sc = (L & 31) ^ (r & 7);           // source chunk (XOR swizzle)
            gload_lds16(YK + (size_t)(key0 + sg) * DSIN + sc * 8,
                        &Kt[b][(size_t)(wave * 4 + c) * 512]);
        }
    };
    // V: chunk L = pt*64 + l2 holds YVb 16B at (kb*256 + pt*16 + (l2&15))*32 + (l2>>4)*8
    auto stageV = [&](int key0, int b) {
#pragma unroll
        for (int c = 0; c < 4; ++c) {
            int L = (wave * 4 + c) * 64 + lane;
            int pt = L >> 6, l2 = L & 63;
            gload_lds16(YVb + ((size_t)(key0 >> 5) * PDIM + pt * 16 + (l2 & 15)) * 32 + (l2 >> 4) * 8,
                        &Vt[b][(size_t)(wave * 4 + c) * 512]);
        }
    };
    stageK(key_begin, 0);
    stageV(key_begin, 0);

    for (int it = 0; it < iters; ++it) {
        const int key0 = key_begin + it * BK;
        const int b = it & 1;
        __syncthreads();   // DMA(it) landed (vmcnt0); buf b^1 reads (it-1) complete

        if (it + 1 < iters) {   // prefetch next tile pair: FULL-iteration window
            stageK(key0 + BK, b ^ 1);
            stageV(key0 + BK, b ^ 1);
        }

        // Swapped QK: s0 over Kt rows 0..15 (keys quad*8+0..3), s1 rows 16..31 (+4..7)
        f32x4 s0 = (f32x4){0.f, 0.f, 0.f, 0.f};
        f32x4 s1 = (f32x4){0.f, 0.f, 0.f, 0.f};
        __builtin_amdgcn_s_setprio(1);
#pragma unroll
        for (int kf = 0; kf < 8; ++kf) {
            int pc = (kf * 4 + quad) ^ swz;        // (16+m16)&7 == m16&7
            s16x8 a0 = *(const s16x8*)(&Kt[b][m16 * 256 + pc * 8]);
            s16x8 a1 = *(const s16x8*)(&Kt[b][(16 + m16) * 256 + pc * 8]);
            s0 = mfma16(a0, qf[kf], s0);           // SWAPPED: A=K, B=Q
            s1 = mfma16(a1, qf[kf], s1);
        }
        __builtin_amdgcn_s_setprio(0);

        // exp/relu + in-register bf16 pack: pa/pb = P[q=m16][keys quad*8+0..7]
        float e0[4], e1[4], r0[4], r1[4];
#pragma unroll
        for (int r = 0; r < 4; ++r) {
            e0[r] = __expf(s0[r]);  r0[r] = fmaxf(s0[r], 0.f);
            e1[r] = __expf(s1[r]);  r1[r] = fmaxf(s1[r], 0.f);
            lacc += e0[r] + e1[r];
            racc += r0[r] + r1[r];
        }
        union { unsigned u[4]; s16x8 v; } pa, pb;
        pa.u[0] = ((unsigned)f2bf(e0[1]) << 16) | f2bf(e0[0]);
        pa.u[1] = ((unsigned)f2bf(e0[3]) << 16) | f2bf(e0[2]);
        pa.u[2] = ((unsigned)f2bf(e1[1]) << 16) | f2bf(e1[0]);
        pa.u[3] = ((unsigned)f2bf(e1[3]) << 16) | f2bf(e1[2]);
        pb.u[0] = ((unsigned)f2bf(r0[1]) << 16) | f2bf(r0[0]);
        pb.u[1] = ((unsigned)f2bf(r0[3]) << 16) | f2bf(r0[2]);
        pb.u[2] = ((unsigned)f2bf(r1[1]) << 16) | f2bf(r1[0]);
        pb.u[3] = ((unsigned)f2bf(r1[3]) << 16) | f2bf(r1[2]);

        // PV: 16 p-tiles, B-frags linear from Vt[b] (conflict-free), dual path
        __builtin_amdgcn_s_setprio(1);
#pragma unroll
        for (int pt = 0; pt < 16; ++pt) {
            s16x8 vf = *(const s16x8*)(&Vt[b][(size_t)(pt * 64 + lane) * 8]);
            aE[pt] = mfma16(pa.v, vf, aE[pt]);
            aR[pt] = mfma16(pb.v, vf, aR[pt]);
        }
        __builtin_amdgcn_s_setprio(0);
    }

    // epilogue: bf16 partial O; PV C-layout row = quad*4+r (q), col = pt*16+m16 (p)
    size_t ob = ((size_t)split * N_Q + qbase) * PDIM;
#pragma unroll
    for (int pt = 0; pt < 16; ++pt)
#pragma unroll
        for (int r = 0; r < 4; ++r) {
            size_t o = ob + (size_t)(wave * 16 + quad * 4 + r) * PDIM + pt * 16 + m16;
            accE[o] = f2bf(aE[pt][r]);
            accR[o] = f2bf(aR[pt][r]);
        }
    // row sums: lane (quad,m16) holds partials for q=m16 over keys quad*8+0..7
    lacc += __shfl_xor(lacc, 16);
    lacc += __shfl_xor(lacc, 32);
    racc += __shfl_xor(racc, 16);
    racc += __shfl_xor(racc, 32);
    if (lane < 16) {
        int row = split * N_Q + qbase + wave * 16 + m16;
        lsum[row] = lacc;
        rsum[row] = racc;
    }
}

// ---------------- K4: combine splits + normalization (bf16 partials in) ----------------
__global__ void k_comb(const u16* __restrict__ accE, const u16* __restrict__ accR,
                       const float* __restrict__ lsum, const float* __restrict__ rsum,
                       float* __restrict__ out, int nsplit) {
    int row = blockIdx.x * 8 + (threadIdx.x >> 5);
    int col = (threadIdx.x & 31) * 8;
    size_t idx = (size_t)row * PDIM + col;
    const size_t NP = (size_t)N_Q * PDIM;
    float E[8] = {0.f, 0.f, 0.f, 0.f, 0.f, 0.f, 0.f, 0.f};
    float R[8] = {0.f, 0.f, 0.f, 0.f, 0.f, 0.f, 0.f, 0.f};
    float L = 0.f, Rs = 0.f;
    for (int s = 0; s < nsplit; ++s) {
        s16x8 e = *(const s16x8*)(accE + s * NP + idx);
        s16x8 r = *(const s16x8*)(accR + s * NP + idx);
#pragma unroll
        for (int j = 0; j < 8; ++j) {
            E[j] += bf2f((u16)e[j]);
            R[j] += bf2f((u16)r[j]);
        }
        L  += lsum[(size_t)s * N_Q + row];
        Rs += rsum[(size_t)s * N_Q + row];
    }
    float invL = 1.f / L, invD = 1.f / (1.f + 0.1f * Rs);
    float4 o0, o1;
    o0.x = (0.1f * R[0] + E[0] * invL) * invD;
    o0.y = (0.1f * R[1] + E[1] * invL) * invD;
    o0.z = (0.1f * R[2] + E[2] * invL) * invD;
    o0.w = (0.1f * R[3] + E[3] * invL) * invD;
    o1.x = (0.1f * R[4] + E[4] * invL) * invD;
    o1.y = (0.1f * R[5] + E[5] * invL) * invD;
    o1.z = (0.1f * R[6] + E[6] * invL) * invD;
    o1.w = (0.1f * R[7] + E[7] * invL) * invD;
    *(float4*)(out + idx) = o0;
    *(float4*)(out + idx + 4) = o1;
}

extern "C" void kernel_launch(void* const* d_in, const int* in_sizes, int n_in,
                              void* d_out, int out_size, void* d_ws, size_t ws_size,
                              hipStream_t stream) {
    const float* x  = (const float*)d_in[0];
    const float* y  = (const float*)d_in[1];
    const float* Wq = (const float*)d_in[2];
    const float* Wk = (const float*)d_in[3];
    const float* Wv = (const float*)d_in[4];
    float* out = (float*)d_out;

    char* ws = (char*)d_ws;
    size_t off = 0;
    auto take = [&](size_t bytes) -> char* {
        char* p = ws + off;
        off += (bytes + 255) & ~(size_t)255;
        return p;
    };
    u16* XQ  = (u16*)take((size_t)N_Q * PDIM * 2);
    u16* WtH = (u16*)take((size_t)PDIM * DSIN * 2);
    u16* WtL = (u16*)take((size_t)PDIM * DSIN * 2);
    u16* YK  = (u16*)take((size_t)MCTX * PDIM * 2);
    u16* YVb = (u16*)take((size_t)MCTX * PDIM * 2);

    size_t perSplit = (size_t)N_Q * PDIM * 2 * 2 + (size_t)N_Q * 4 * 2 + 1024;
    int nsplit = (ws_size >= off + 2 * perSplit + 4096) ? 2 : 1;

    u16*   accE = (u16*)take((size_t)nsplit * N_Q * PDIM * 2);
    u16*   accR = (u16*)take((size_t)nsplit * N_Q * PDIM * 2);
    float* lsum = (float*)take((size_t)nsplit * N_Q * 4);
    float* rsum = (float*)take((size_t)nsplit * N_Q * 4);

    hipLaunchKernelGGL(k_prep, dim3(PDIM + MCTX/32), dim3(256), 0, stream,
                       Wq, WtH, WtL, y, Wk, Wv, YK, YVb);
    hipLaunchKernelGGL(k_xq,   dim3(N_Q/32), dim3(256), 0, stream, x, WtH, WtL, XQ);
    hipLaunchKernelGGL(k_attn, dim3(N_Q/64, nsplit), dim3(256), 0, stream,
                       XQ, YK, YVb, accE, accR, lsum, rsum, MCTX / nsplit);
    hipLaunchKernelGGL(k_comb, dim3(N_Q/8), dim3(256), 0, stream,
                       accE, accR, lsum, rsum, out, nsplit);
}

// Round 14
// 221.771 us; speedup vs baseline: 1.0440x; 1.0440x over previous
//
#include <hip/hip_runtime.h>
#include <hip/hip_bf16.h>

#define N_Q   16384
#define MCTX  4096
#define DSIN  256
#define YDIM  7
#define PDIM  256   // SPROJ
#define BK    32

typedef __attribute__((ext_vector_type(8))) short s16x8;   // 8 bf16 (4 VGPRs)
typedef __attribute__((ext_vector_type(4))) float f32x4;   // MFMA C/D frag
typedef unsigned short u16;

static __device__ __forceinline__ u16 f2bf(float f) {
    union { float f; unsigned u; } v; v.f = f;
    unsigned r = v.u + 0x7fffu + ((v.u >> 16) & 1u);  // RNE
    return (u16)(r >> 16);
}
static __device__ __forceinline__ float bf2f(u16 h) {
    union { unsigned u; float f; } v; v.u = ((unsigned)h) << 16;
    return v.f;
}
// HW bf16 converts (compiler emits v_cvt_pk_bf16_f32; RNE == f2bf numerics)
static __device__ __forceinline__ unsigned pk2bf(float lo, float hi) {
    __hip_bfloat162 h2 = __float22bfloat162_rn(make_float2(lo, hi));
    union { __hip_bfloat162 h; unsigned u; } v; v.h = h2;
    return v.u;  // lo in bits [15:0], hi in [31:16]
}
static __device__ __forceinline__ u16 f2bf_hw(float f) {
    __hip_bfloat16 h = __float2bfloat16(f);
    union { __hip_bfloat16 h; u16 u; } v; v.h = h;
    return v.u;
}
static __device__ __forceinline__ f32x4 mfma16(s16x8 a, s16x8 b, f32x4 c) {
    return __builtin_amdgcn_mfma_f32_16x16x32_bf16(a, b, c, 0, 0, 0);
}
// async 16B global->LDS DMA (dst = wave-uniform base + lane*16)
static __device__ __forceinline__ void gload_lds16(const u16* g, u16* l) {
    __builtin_amdgcn_global_load_lds(
        (const __attribute__((address_space(1))) unsigned int*)(g),
        (__attribute__((address_space(3))) unsigned int*)(l), 16, 0, 0);
}

// ---------------- K_prep: (a) Wq transpose + hi/lo split, (b) YK + YVb ----------------
__global__ void k_prep(const float* __restrict__ Wq, u16* __restrict__ WtH,
                       u16* __restrict__ WtL, const float* __restrict__ y,
                       const float* __restrict__ Wk, const float* __restrict__ Wv,
                       u16* __restrict__ YK, u16* __restrict__ YVb) {
    if (blockIdx.x < PDIM) {
        int n = blockIdx.x;   // 0..PDIM-1
        int k = threadIdx.x;  // 0..DSIN-1
        float w = Wq[(size_t)k * PDIM + n];
        u16 h = f2bf(w);
        WtH[(size_t)n * DSIN + k] = h;
        WtL[(size_t)n * DSIN + k] = f2bf(w - bf2f(h));
    } else {
        // YK scaled 1/16 row-major [key][p]; YVb coalesced PV-frag layout [kb][p][32]
        int kb = blockIdx.x - PDIM;  // key block (32 keys)
        int p  = threadIdx.x;        // proj
        float wk[YDIM], wv[YDIM];
#pragma unroll
        for (int j = 0; j < YDIM; ++j) {
            wk[j] = Wk[(size_t)j * PDIM + p];
            wv[j] = Wv[(size_t)j * PDIM + p];
        }
        u16 vbuf[32];
#pragma unroll
        for (int m = 0; m < 32; ++m) {
            int key = kb * 32 + m;
            float ak = 0.f, av = 0.f;
#pragma unroll
            for (int j = 0; j < YDIM; ++j) {
                float yy = y[(size_t)key * YDIM + j];
                ak += yy * wk[j];
                av += yy * wv[j];
            }
            YK[(size_t)key * PDIM + p] = f2bf(ak * 0.0625f);  // fold 1/sqrt(256)
            vbuf[m] = f2bf(av);
        }
        s16x8* dst = (s16x8*)(YVb + ((size_t)kb * PDIM + p) * 32);
#pragma unroll
        for (int c = 0; c < 4; ++c) dst[c] = ((s16x8*)vbuf)[c];
    }
}

// ---------------- K1: XQ = x @ Wq, hi/lo split; 32-row tiles, 2 blocks/CU ----------------
__global__ __launch_bounds__(256, 2) void k_xq(const float* __restrict__ x,
                                               const u16* __restrict__ WtH,
                                               const u16* __restrict__ WtL,
                                               u16* __restrict__ XQ) {
    __shared__ u16 xH[32 * 256];  // XOR-swizzled 16B chunks: phys c = c ^ (row&7)
    __shared__ u16 xL[32 * 256];
    const int tid = threadIdx.x;
    const int rowg0 = blockIdx.x * 32;
#pragma unroll
    for (int i = 0; i < 4; ++i) {
        int row = (tid >> 5) + i * 8;
        int c32 = tid & 31;
        const float* px = x + (size_t)(rowg0 + row) * DSIN + c32 * 8;
        float4 a = *(const float4*)px;
        float4 b = *(const float4*)(px + 4);
        float vals[8] = {a.x, a.y, a.z, a.w, b.x, b.y, b.z, b.w};
        s16x8 h, l;
#pragma unroll
        for (int j = 0; j < 8; ++j) {
            u16 hh = f2bf(vals[j]);
            h[j] = (short)hh;
            l[j] = (short)f2bf(vals[j] - bf2f(hh));
        }
        int pc = c32 ^ (row & 7);
        *(s16x8*)(xH + row * 256 + pc * 8) = h;
        *(s16x8*)(xL + row * 256 + pc * 8) = l;
    }
    __syncthreads();

    const int wave = tid >> 6, lane = tid & 63;
    const int quad = lane >> 4, m16 = lane & 15;
    const int rh = wave & 1, ph = wave >> 1;
    const int rowl = rh * 16 + m16;
    const int swz = rowl & 7;
    s16x8 ah[8], al[8];
#pragma unroll
    for (int kf = 0; kf < 8; ++kf) {
        int pc = (kf * 4 + quad) ^ swz;
        ah[kf] = *(const s16x8*)(xH + rowl * 256 + pc * 8);
        al[kf] = *(const s16x8*)(xL + rowl * 256 + pc * 8);
    }
#pragma unroll
    for (int ptl = 0; ptl < 8; ++ptl) {
        int pt = ph * 8 + ptl;
        f32x4 acc = (f32x4){0.f, 0.f, 0.f, 0.f};
#pragma unroll
        for (int kf = 0; kf < 8; ++kf) {
            size_t idx = (size_t)(pt * 16 + m16) * DSIN + kf * 32 + quad * 8;
            s16x8 bh = *(const s16x8*)(WtH + idx);
            s16x8 bl = *(const s16x8*)(WtL + idx);
            acc = mfma16(ah[kf], bh, acc);
            acc = mfma16(al[kf], bh, acc);
            acc = mfma16(ah[kf], bl, acc);
        }
#pragma unroll
        for (int r = 0; r < 4; ++r)
            XQ[(size_t)(rowg0 + rh * 16 + quad * 4 + r) * PDIM + pt * 16 + m16] =
                f2bf(acc[r]);
    }
}

// ---------------- K3: fused attention — R12 structure + HW cvt_pk bf16 packing ----
// Block: 64 q x 256 p, 4 waves. Wave w: S-quarter (rows w*16..+16) via QK; exp/relu in
// C-layout -> bf16 Pe/Pr LDS; PV over p-slice [64w,64w+64) using all Pe/Pr.
// EVEN/ODD key pairing (R12-verified): QK B-frags cover keys 2*m16 / 2*m16+1 -> a lane's
// two S values are ADJACENT keys -> packed b32 Pe/Pr writes. NEW: packing uses
// __float22bfloat162_rn (HW v_cvt_pk_bf16_f32, RNE) instead of manual bit-twiddled RNE
// (~56 fewer VALU ops per lane-iter on the serial QK->publish chain).
__global__ __launch_bounds__(256, 2) void k_attn(const u16* __restrict__ XQ,
                                                 const u16* __restrict__ YK,
                                                 const u16* __restrict__ YVb,
                                                 u16* __restrict__ accE,
                                                 u16* __restrict__ accR,
                                                 float* __restrict__ lsum,
                                                 float* __restrict__ rsum,
                                                 int msPerSplit) {
    __shared__ u16 Kt[32 * 256];   // 32 keys x 256 d, XOR-swizzled chunks
    __shared__ u16 Pe[64 * 40];    // 64 q x 32 keys, pad->40
    __shared__ u16 Pr[64 * 40];

    const int tid = threadIdx.x;
    const int wave = tid >> 6, lane = tid & 63;
    const int quad = lane >> 4, m16 = lane & 15;
    const int split = blockIdx.y;
    const int qbase = blockIdx.x * 64;
    const int key_begin = split * msPerSplit;
    const int iters = msPerSplit / BK;
    const int pslice = wave * 64;
    const int kr0 = m16 + m16;          // this lane's two K rows (adjacent keys)
    const int swz0 = kr0 & 7;           // (kr0+1)&7 == swz0^1 (kr0 even)

    // Q A-frags for this wave's 16 S-rows
    s16x8 qf[8];
    const u16* qp = XQ + (size_t)(qbase + wave * 16 + m16) * DSIN;
#pragma unroll
    for (int kf = 0; kf < 8; ++kf)
        qf[kf] = *(const s16x8*)(qp + kf * 32 + quad * 8);

    f32x4 aE[4][4], aR[4][4];
#pragma unroll
    for (int g = 0; g < 4; ++g)
#pragma unroll
        for (int t = 0; t < 4; ++t) {
            aE[g][t] = (f32x4){0.f, 0.f, 0.f, 0.f};
            aR[g][t] = (f32x4){0.f, 0.f, 0.f, 0.f};
        }
    float lacc[4] = {0.f, 0.f, 0.f, 0.f}, racc[4] = {0.f, 0.f, 0.f, 0.f};

    // stage K tile for key0 via DMA; source chunk XOR-permuted so phys layout is swizzled
    auto stage = [&](int key0) {
#pragma unroll
        for (int c = 0; c < 4; ++c) {
            int l = (wave * 4 + c) * 64 + lane;   // phys chunk 0..1023
            int r = l >> 5;                        // key row 0..31
            int sc = (l & 31) ^ (r & 7);           // source chunk in row
            gload_lds16(YK + (size_t)(key0 + r) * DSIN + sc * 8,
                        Kt + (size_t)(wave * 4 + c) * 512);
        }
    };
    stage(key_begin);

    for (int it = 0; it < iters; ++it) {
        const int key0 = key_begin + it * BK;
        __syncthreads();   // Kt(it) visible (vmcnt0 + barrier)

        // QK: S-quarter rows wave*16+quad*4+r, key columns 2*m16 / 2*m16+1
        f32x4 s0 = (f32x4){0.f, 0.f, 0.f, 0.f};
        f32x4 s1 = (f32x4){0.f, 0.f, 0.f, 0.f};
        __builtin_amdgcn_s_setprio(1);
#pragma unroll
        for (int kf = 0; kf < 8; ++kf) {
            int pc0 = (kf * 4 + quad) ^ swz0;
            int pc1 = pc0 ^ 1;
            s16x8 b0 = *(const s16x8*)(Kt + kr0 * 256 + pc0 * 8);
            s16x8 b1 = *(const s16x8*)(Kt + (kr0 + 1) * 256 + pc1 * 8);
            s0 = mfma16(qf[kf], b0, s0);
            s1 = mfma16(qf[kf], b1, s1);
        }
        __builtin_amdgcn_s_setprio(0);
        // exp/relu in C-layout; per-lane partial row sums; HW cvt_pk -> packed b32 Pe/Pr
#pragma unroll
        for (int r = 0; r < 4; ++r) {
            float e0 = __expf(s0[r]), e1 = __expf(s1[r]);
            float rl0 = fmaxf(s0[r], 0.f), rl1 = fmaxf(s1[r], 0.f);
            lacc[r] += e0 + e1;
            racc[r] += rl0 + rl1;
            int row = wave * 16 + quad * 4 + r;
            *(unsigned*)(Pe + row * 40 + kr0) = pk2bf(e0, e1);
            *(unsigned*)(Pr + row * 40 + kr0) = pk2bf(rl0, rl1);
        }
        __syncthreads();   // Pe/Pr visible; Kt free to overwrite

        // V-frags first (so their vmcnt wait doesn't drain the DMA below)
        s16x8 vf[4];
        const u16* vb = YVb + (size_t)((key0 >> 5) * PDIM) * 32;
#pragma unroll
        for (int t = 0; t < 4; ++t)
            vf[t] = *(const s16x8*)(vb + (size_t)(pslice + t * 16 + m16) * 32 + quad * 8);

        if (it + 1 < iters) stage(key0 + BK);  // async prefetch of next K tile

        // PV: dual path, V-frag reused 8x, Pe/Pr A-frags from LDS
        __builtin_amdgcn_s_setprio(1);
#pragma unroll
        for (int g = 0; g < 4; ++g) {
            s16x8 pa = *(const s16x8*)(Pe + (g * 16 + m16) * 40 + quad * 8);
            s16x8 pb = *(const s16x8*)(Pr + (g * 16 + m16) * 40 + quad * 8);
#pragma unroll
            for (int t = 0; t < 4; ++t) {
                aE[g][t] = mfma16(pa, vf[t], aE[g][t]);
                aR[g][t] = mfma16(pb, vf[t], aR[g][t]);
            }
        }
        __builtin_amdgcn_s_setprio(0);
    }

    // epilogue: bf16 partial O (HW converts) and row sums
    size_t ob = ((size_t)split * N_Q + qbase) * PDIM;
#pragma unroll
    for (int g = 0; g < 4; ++g)
#pragma unroll
        for (int t = 0; t < 4; ++t)
#pragma unroll
            for (int r = 0; r < 4; ++r) {
                size_t o = ob + (size_t)(g * 16 + quad * 4 + r) * PDIM + pslice + t * 16 + m16;
                accE[o] = f2bf_hw(aE[g][t][r]);
                accR[o] = f2bf_hw(aR[g][t][r]);
            }
#pragma unroll
    for (int r = 0; r < 4; ++r) {
        lacc[r] += __shfl_xor(lacc[r], 1);
        lacc[r] += __shfl_xor(lacc[r], 2);
        lacc[r] += __shfl_xor(lacc[r], 4);
        lacc[r] += __shfl_xor(lacc[r], 8);
        racc[r] += __shfl_xor(racc[r], 1);
        racc[r] += __shfl_xor(racc[r], 2);
        racc[r] += __shfl_xor(racc[r], 4);
        racc[r] += __shfl_xor(racc[r], 8);
    }
    if (m16 < 4) {
        float lv = (m16 == 0) ? lacc[0] : (m16 == 1) ? lacc[1] : (m16 == 2) ? lacc[2] : lacc[3];
        float rv = (m16 == 0) ? racc[0] : (m16 == 1) ? racc[1] : (m16 == 2) ? racc[2] : racc[3];
        int row = split * N_Q + qbase + wave * 16 + quad * 4 + m16;
        lsum[row] = lv;
        rsum[row] = rv;
    }
}

// ---------------- K4: combine splits + normalization (bf16 partials in) ----------------
__global__ void k_comb(const u16* __restrict__ accE, const u16* __restrict__ accR,
                       const float* __restrict__ lsum, const float* __restrict__ rsum,
                       float* __restrict__ out, int nsplit) {
    int row = blockIdx.x * 8 + (threadIdx.x >> 5);
    int col = (threadIdx.x & 31) * 8;
    size_t idx = (size_t)row * PDIM + col;
    const size_t NP = (size_t)N_Q * PDIM;
    float E[8] = {0.f, 0.f, 0.f, 0.f, 0.f, 0.f, 0.f, 0.f};
    float R[8] = {0.f, 0.f, 0.f, 0.f, 0.f, 0.f, 0.f, 0.f};
    float L = 0.f, Rs = 0.f;
    for (int s = 0; s < nsplit; ++s) {
        s16x8 e = *(const s16x8*)(accE + s * NP + idx);
        s16x8 r = *(const s16x8*)(accR + s * NP + idx);
#pragma unroll
        for (int j = 0; j < 8; ++j) {
            E[j] += bf2f((u16)e[j]);
            R[j] += bf2f((u16)r[j]);
        }
        L  += lsum[(size_t)s * N_Q + row];
        Rs += rsum[(size_t)s * N_Q + row];
    }
    float invL = 1.f / L, invD = 1.f / (1.f + 0.1f * Rs);
    float4 o0, o1;
    o0.x = (0.1f * R[0] + E[0] * invL) * invD;
    o0.y = (0.1f * R[1] + E[1] * invL) * invD;
    o0.z = (0.1f * R[2] + E[2] * invL) * invD;
    o0.w = (0.1f * R[3] + E[3] * invL) * invD;
    o1.x = (0.1f * R[4] + E[4] * invL) * invD;
    o1.y = (0.1f * R[5] + E[5] * invL) * invD;
    o1.z = (0.1f * R[6] + E[6] * invL) * invD;
    o1.w = (0.1f * R[7] + E[7] * invL) * invD;
    *(float4*)(out + idx) = o0;
    *(float4*)(out + idx + 4) = o1;
}

extern "C" void kernel_launch(void* const* d_in, const int* in_sizes, int n_in,
                              void* d_out, int out_size, void* d_ws, size_t ws_size,
                              hipStream_t stream) {
    const float* x  = (const float*)d_in[0];
    const float* y  = (const float*)d_in[1];
    const float* Wq = (const float*)d_in[2];
    const float* Wk = (const float*)d_in[3];
    const float* Wv = (const float*)d_in[4];
    float* out = (float*)d_out;

    char* ws = (char*)d_ws;
    size_t off = 0;
    auto take = [&](size_t bytes) -> char* {
        char* p = ws + off;
        off += (bytes + 255) & ~(size_t)255;
        return p;
    };
    u16* XQ  = (u16*)take((size_t)N_Q * PDIM * 2);
    u16* WtH = (u16*)take((size_t)PDIM * DSIN * 2);
    u16* WtL = (u16*)take((size_t)PDIM * DSIN * 2);
    u16* YK  = (u16*)take((size_t)MCTX * PDIM * 2);
    u16* YVb = (u16*)take((size_t)MCTX * PDIM * 2);

    size_t perSplit = (size_t)N_Q * PDIM * 2 * 2 + (size_t)N_Q * 4 * 2 + 1024;
    int nsplit = (ws_size >= off + 2 * perSplit + 4096) ? 2 : 1;

    u16*   accE = (u16*)take((size_t)nsplit * N_Q * PDIM * 2);
    u16*   accR = (u16*)take((size_t)nsplit * N_Q * PDIM * 2);
    float* lsum = (float*)take((size_t)nsplit * N_Q * 4);
    float* rsum = (float*)take((size_t)nsplit * N_Q * 4);

    hipLaunchKernelGGL(k_prep, dim3(PDIM + MCTX/32), dim3(256), 0, stream,
                       Wq, WtH, WtL, y, Wk, Wv, YK, YVb);
    hipLaunchKernelGGL(k_xq,   dim3(N_Q/32), dim3(256), 0, stream, x, WtH, WtL, XQ);
    hipLaunchKernelGGL(k_attn, dim3(N_Q/64, nsplit), dim3(256), 0, stream,
                       XQ, YK, YVb, accE, accR, lsum, rsum, MCTX / nsplit);
    hipLaunchKernelGGL(k_comb, dim3(N_Q/8), dim3(256), 0, stream,
                       accE, accR, lsum, rsum, out, nsplit);
}